// Round 11
// baseline (1574.603 us; speedup 1.0000x reference)
//
#include <hip/hip_runtime.h>
#include <hip/hip_bf16.h>
#include <math.h>

// GCN 2-layer: x[N,128] @ W1 -> agg -> relu -> @ W2 -> agg -> log_softmax
// N=100000, E=1600000, F=128, H=64, C=40
// Bucket-sorted edge list (coarse only, no within-bucket sort).
// Agg = block-per-bucket: 128x64 f32 accumulator in 32KB LDS, ds_add_f32.
// Layer 2 reordered: A@(y@W2) == (A@y)@W2.

#define NFEAT 128
#define HID 64
#define NCLS 40
#define PB 512          // partition blocks for hist/bucketize
#define BSH 7           // 128 nodes per bucket
#define NBUK_MAX 1024

static __device__ __forceinline__ unsigned short f2bf(float f) {
    unsigned u = __float_as_uint(f);
    unsigned r = (u + 0x7fffu + ((u >> 16) & 1u)) >> 16;
    return (unsigned short)r;
}
static __device__ __forceinline__ float bf2f(unsigned short b) {
    return __uint_as_float(((unsigned)b) << 16);
}

// ---------- Pass A: per-block bucket histogram ----------
__global__ __launch_bounds__(256) void k_hist(const int* __restrict__ dst,
                                              int* __restrict__ ghist,
                                              int e, int nbuk, int epb) {
    __shared__ int hist[NBUK_MAX];
    for (int j = threadIdx.x; j < nbuk; j += 256) hist[j] = 0;
    __syncthreads();
    int b = blockIdx.x;
    int lo = b * epb, hi = min(lo + epb, e);
    for (int i = lo + threadIdx.x; i < hi; i += 256)
        atomicAdd(&hist[dst[i] >> BSH], 1);
    __syncthreads();
    for (int j = threadIdx.x; j < nbuk; j += 256) ghist[j * PB + b] = hist[j];
}

// ---------- Pass B1: exclusive scan of each bucket's column (in place) ----------
__global__ __launch_bounds__(256) void k_colscan(int* __restrict__ ghist,
                                                 int* __restrict__ buktot, int nbuk) {
    __shared__ int s[256];
    int k = blockIdx.x, t = threadIdx.x;
    int* col = ghist + k * PB;
    int v0 = col[2 * t], v1 = col[2 * t + 1];
    int sum = v0 + v1;
    s[t] = sum; __syncthreads();
    for (int off = 1; off < 256; off <<= 1) {
        int x = (t >= off) ? s[t - off] : 0;
        __syncthreads();
        s[t] += x;
        __syncthreads();
    }
    int excl = s[t] - sum;
    col[2 * t] = excl;
    col[2 * t + 1] = excl + v0;
    if (t == 255) buktot[k] = s[255];
}

// ---------- Pass B2: scan bucket totals -> bukstart ----------
__global__ __launch_bounds__(256) void k_bukscan(const int* __restrict__ buktot,
                                                 int* __restrict__ bukstart,
                                                 int nbuk) {
    __shared__ int s[256];
    int t = threadIdx.x;
    int v[4]; int sum = 0;
#pragma unroll
    for (int j = 0; j < 4; j++) { int idx = t * 4 + j; v[j] = (idx < nbuk) ? buktot[idx] : 0; sum += v[j]; }
    s[t] = sum; __syncthreads();
    for (int off = 1; off < 256; off <<= 1) {
        int x = (t >= off) ? s[t - off] : 0;
        __syncthreads();
        s[t] += x;
        __syncthreads();
    }
    int excl = s[t] - sum;
#pragma unroll
    for (int j = 0; j < 4; j++) { int idx = t * 4 + j; if (idx < nbuk) bukstart[idx] = excl; excl += v[j]; }
    if (t == 255) bukstart[nbuk] = s[255];
}

// ---------- Pass C: scatter edges into bucket regions (order within bucket irrelevant) ----------
__global__ __launch_bounds__(256) void k_bucketize(const int* __restrict__ src,
                                                   const int* __restrict__ dst,
                                                   const float* __restrict__ w,
                                                   const int* __restrict__ ghist,
                                                   const int* __restrict__ bukstart,
                                                   unsigned long long* __restrict__ sedge,
                                                   int e, int nbuk, int epb) {
    __shared__ int loff[NBUK_MAX];
    int b = blockIdx.x;
    for (int j = threadIdx.x; j < nbuk; j += 256) loff[j] = bukstart[j] + ghist[j * PB + b];
    __syncthreads();
    int lo = b * epb, hi = min(lo + epb, e);
    for (int i = lo + threadIdx.x; i < hi; i += 256) {
        int d = dst[i], s = src[i];
        int k = d >> BSH;
        int pos = atomicAdd(&loff[k], 1);
        unsigned long long rec = ((unsigned long long)__float_as_uint(w[i]) << 32)
                               | ((unsigned)(d & 127) << 17) | (unsigned)s;
        sedge[pos] = rec;
    }
}

// ---------- Pass D: per-bucket weighted degree -> dinv ----------
__global__ __launch_bounds__(256) void k_deg(const unsigned long long* __restrict__ sedge,
                                             const int* __restrict__ bukstart,
                                             float* __restrict__ dinv, int n) {
    __shared__ float wsum[128];
    int k = blockIdx.x, t = threadIdx.x;
    int base = k << BSH;
    int nloc = n - base; if (nloc > 128) nloc = 128;
    if (t < 128) wsum[t] = 1.0f;            // self-loop weight
    __syncthreads();
    int lo = bukstart[k], hi = bukstart[k + 1];
    for (int p = lo + t; p < hi; p += 256) {
        unsigned long long r = sedge[p];
        atomicAdd(&wsum[(int)((r >> 17) & 127)], __uint_as_float((unsigned)(r >> 32)));
    }
    __syncthreads();
    if (t < nloc) dinv[base + t] = rsqrtf(wsum[t]);
}

// ---------- GEMM1: 64-row tiles, x transposed in LDS, bf16 output ----------
__global__ __launch_bounds__(256) void k_gemm1(const float* __restrict__ x,
                                               const float* __restrict__ W1,
                                               unsigned short* __restrict__ h1, int n) {
    __shared__ float xs[64 * 65];
    int t = threadIdx.x;
    int lane = t & 63;
    int wid = __builtin_amdgcn_readfirstlane(t >> 6);
    int base = blockIdx.x * 64;
    int nrows = n - base; if (nrows > 64) nrows = 64;
    const float4* xg = reinterpret_cast<const float4*>(x + (size_t)base * NFEAT);
    float acc[16];
#pragma unroll
    for (int c = 0; c < 16; c++) acc[c] = 0.f;
#pragma unroll
    for (int h = 0; h < 2; h++) {
        for (int j = t; j < nrows * 16; j += 256) {
            int row = j >> 4, k4 = j & 15;
            float4 v = xg[row * 32 + h * 16 + k4];
            xs[(4 * k4 + 0) * 65 + row] = v.x;
            xs[(4 * k4 + 1) * 65 + row] = v.y;
            xs[(4 * k4 + 2) * 65 + row] = v.z;
            xs[(4 * k4 + 3) * 65 + row] = v.w;
        }
        __syncthreads();
        const float* wb = W1 + (size_t)(h * 64) * HID + wid * 16;
#pragma unroll 4
        for (int k = 0; k < 64; k++) {
            float xv = xs[k * 65 + lane];
            const float* wk = wb + k * HID;
#pragma unroll
            for (int c = 0; c < 16; c++) acc[c] = fmaf(wk[c], xv, acc[c]);
        }
        __syncthreads();
    }
    if (lane < nrows) {
        unsigned pk[8];
#pragma unroll
        for (int j = 0; j < 8; j++)
            pk[j] = (unsigned)f2bf(acc[2 * j]) | ((unsigned)f2bf(acc[2 * j + 1]) << 16);
        uint4* hp = reinterpret_cast<uint4*>(h1 + (size_t)(base + lane) * HID + wid * 16);
        hp[0] = make_uint4(pk[0], pk[1], pk[2], pk[3]);
        hp[1] = make_uint4(pk[4], pk[5], pk[6], pk[7]);
    }
}

// ---------- agg1f: block-per-bucket, 32KB LDS acc, y = relu(A@h1+b1) bf16 ----------
__global__ __launch_bounds__(512) void k_agg1f(const unsigned short* __restrict__ h1,
                                               const unsigned long long* __restrict__ sedge,
                                               const int* __restrict__ bukstart,
                                               const float* __restrict__ dinv,
                                               const float* __restrict__ b1,
                                               unsigned short* __restrict__ y, int n) {
    __shared__ float acc[128 * HID];
    __shared__ float dl[128];
    int t = threadIdx.x, lane = t & 63, wv = t >> 6;   // 8 waves
    int k = blockIdx.x, base = k << BSH;
    int nloc = n - base; if (nloc > 128) nloc = 128;
    float4* a4 = reinterpret_cast<float4*>(acc);
    for (int j = t; j < 128 * HID / 4; j += 512) a4[j] = make_float4(0.f, 0.f, 0.f, 0.f);
    if (t < 128) dl[t] = (t < nloc) ? dinv[base + t] : 0.f;
    __syncthreads();
    int lo = bukstart[k], hi = bukstart[k + 1];
    int p0 = lo + wv * 8;
    for (; p0 + 8 <= hi; p0 += 64) {
        unsigned long long r[8];
#pragma unroll
        for (int j = 0; j < 8; j++) r[j] = sedge[p0 + j];
        int s[8], d[8];
#pragma unroll
        for (int j = 0; j < 8; j++) { s[j] = (int)(r[j] & 0x1ffff); d[j] = (int)((r[j] >> 17) & 127); }
        float hv[8];
#pragma unroll
        for (int j = 0; j < 8; j++) hv[j] = bf2f(h1[(size_t)s[j] * HID + lane]);
        float nm[8];
#pragma unroll
        for (int j = 0; j < 8; j++) nm[j] = __uint_as_float((unsigned)(r[j] >> 32)) * dinv[s[j]] * dl[d[j]];
#pragma unroll
        for (int j = 0; j < 8; j++) atomicAdd(&acc[d[j] * HID + lane], nm[j] * hv[j]);
    }
    for (int q = p0; q < hi && q < p0 + 8; q++) {
        unsigned long long r = sedge[q];
        int sq = (int)(r & 0x1ffff), dq = (int)((r >> 17) & 127);
        float nm = __uint_as_float((unsigned)(r >> 32)) * dinv[sq] * dl[dq];
        atomicAdd(&acc[dq * HID + lane], nm * bf2f(h1[(size_t)sq * HID + lane]));
    }
    __syncthreads();
    float bl = b1[lane];
    for (int rr = wv; rr < nloc; rr += 8) {
        float di = dl[rr];
        float val = acc[rr * HID + lane] + di * di * bf2f(h1[(size_t)(base + rr) * HID + lane]) + bl;
        y[(size_t)(base + rr) * HID + lane] = f2bf(fmaxf(val, 0.f));
    }
}

// ---------- aggzf: block-per-bucket, z = A@y (f32 out) ----------
__global__ __launch_bounds__(512) void k_aggzf(const unsigned short* __restrict__ y,
                                               const unsigned long long* __restrict__ sedge,
                                               const int* __restrict__ bukstart,
                                               const float* __restrict__ dinv,
                                               float* __restrict__ z, int n) {
    __shared__ float acc[128 * HID];
    __shared__ float dl[128];
    int t = threadIdx.x, lane = t & 63, wv = t >> 6;
    int k = blockIdx.x, base = k << BSH;
    int nloc = n - base; if (nloc > 128) nloc = 128;
    float4* a4 = reinterpret_cast<float4*>(acc);
    for (int j = t; j < 128 * HID / 4; j += 512) a4[j] = make_float4(0.f, 0.f, 0.f, 0.f);
    if (t < 128) dl[t] = (t < nloc) ? dinv[base + t] : 0.f;
    __syncthreads();
    int lo = bukstart[k], hi = bukstart[k + 1];
    int p0 = lo + wv * 8;
    for (; p0 + 8 <= hi; p0 += 64) {
        unsigned long long r[8];
#pragma unroll
        for (int j = 0; j < 8; j++) r[j] = sedge[p0 + j];
        int s[8], d[8];
#pragma unroll
        for (int j = 0; j < 8; j++) { s[j] = (int)(r[j] & 0x1ffff); d[j] = (int)((r[j] >> 17) & 127); }
        float hv[8];
#pragma unroll
        for (int j = 0; j < 8; j++) hv[j] = bf2f(y[(size_t)s[j] * HID + lane]);
        float nm[8];
#pragma unroll
        for (int j = 0; j < 8; j++) nm[j] = __uint_as_float((unsigned)(r[j] >> 32)) * dinv[s[j]] * dl[d[j]];
#pragma unroll
        for (int j = 0; j < 8; j++) atomicAdd(&acc[d[j] * HID + lane], nm[j] * hv[j]);
    }
    for (int q = p0; q < hi && q < p0 + 8; q++) {
        unsigned long long r = sedge[q];
        int sq = (int)(r & 0x1ffff), dq = (int)((r >> 17) & 127);
        float nm = __uint_as_float((unsigned)(r >> 32)) * dinv[sq] * dl[dq];
        atomicAdd(&acc[dq * HID + lane], nm * bf2f(y[(size_t)sq * HID + lane]));
    }
    __syncthreads();
    for (int rr = wv; rr < nloc; rr += 8) {
        float di = dl[rr];
        float val = acc[rr * HID + lane] + di * di * bf2f(y[(size_t)(base + rr) * HID + lane]);
        z[(size_t)(base + rr) * HID + lane] = val;
    }
}

// ---------- gemm2s: out = log_softmax(z @ W2 + b2) (dense, streaming) ----------
__global__ __launch_bounds__(256) void k_gemm2s(const float* __restrict__ z,
                                                const float* __restrict__ W2,
                                                const float* __restrict__ b2,
                                                float* __restrict__ out, int n) {
    __shared__ float ys[HID * 65];      // transposed z tile [k][row]
    __shared__ float zs[64 * 41];       // logits [row][col(40)], stride 41
    int t = threadIdx.x;
    int lane = t & 63;
    int wid = __builtin_amdgcn_readfirstlane(t >> 6);
    int base = blockIdx.x * 64;
    int nrows = n - base; if (nrows > 64) nrows = 64;
    const float4* yg = reinterpret_cast<const float4*>(z + (size_t)base * HID);
    for (int j = t; j < nrows * 16; j += 256) {
        int row = j >> 4, k4 = j & 15;
        float4 v = yg[j];
        ys[(4 * k4 + 0) * 65 + row] = v.x;
        ys[(4 * k4 + 1) * 65 + row] = v.y;
        ys[(4 * k4 + 2) * 65 + row] = v.z;
        ys[(4 * k4 + 3) * 65 + row] = v.w;
    }
    __syncthreads();
    const float* wb = W2 + wid * 10;
    float acc[10];
#pragma unroll
    for (int c = 0; c < 10; c++) acc[c] = b2[wid * 10 + c];
#pragma unroll 4
    for (int k = 0; k < HID; k++) {
        float yv = ys[k * 65 + lane];
        const float* wk = wb + k * NCLS;
#pragma unroll
        for (int c = 0; c < 10; c++) acc[c] = fmaf(wk[c], yv, acc[c]);
    }
#pragma unroll
    for (int c = 0; c < 10; c++) zs[lane * 41 + wid * 10 + c] = acc[c];
    __syncthreads();
    if (lane < nrows) {
        const float* zr = zs + lane * 41;
        float m = zr[0];
#pragma unroll
        for (int j = 1; j < NCLS; j++) m = fmaxf(m, zr[j]);
        float sum = 0.f;
#pragma unroll
        for (int j = 0; j < NCLS; j++) sum += expf(zr[j] - m);
        float lse = m + logf(sum);
        float2* op = reinterpret_cast<float2*>(out + (size_t)(base + lane) * NCLS + wid * 10);
#pragma unroll
        for (int j = 0; j < 5; j++)
            op[j] = make_float2(acc[2 * j] - lse, acc[2 * j + 1] - lse);
    }
}

// ---------------- launch ----------------

extern "C" void kernel_launch(void* const* d_in, const int* in_sizes, int n_in,
                              void* d_out, int out_size, void* d_ws, size_t ws_size,
                              hipStream_t stream) {
    const float* x = (const float*)d_in[0];
    const int* edge_index = (const int*)d_in[1];
    const float* ew = (const float*)d_in[2];
    const float* W1 = (const float*)d_in[3];
    const float* b1 = (const float*)d_in[4];
    const float* W2 = (const float*)d_in[5];
    const float* b2 = (const float*)d_in[6];
    float* out = (float*)d_out;

    const int N = in_sizes[0] / NFEAT;      // 100000
    const int E = in_sizes[2];              // 1600000
    const int* src = edge_index;
    const int* dst = edge_index + E;

    const int NBUK = (N + 127) >> BSH;      // 782
    const int EPB = (E + PB - 1) / PB;      // 3125

    char* ws = (char*)d_ws;
    size_t off = 0;
    auto alloc = [&](size_t bytes) { void* p = ws + off; off = (off + bytes + 255) & ~(size_t)255; return p; };
    int*   ghist    = (int*)alloc((size_t)NBUK_MAX * PB * 4);   // 2 MB
    int*   buktot   = (int*)alloc(4096);
    int*   bukstart = (int*)alloc(4096 + 4);
    float* dinv     = (float*)alloc((size_t)N * 4);
    unsigned long long* sedge = (unsigned long long*)alloc((size_t)E * 8);  // 12.8 MB, lives to aggzf
    unsigned short* ybuf = (unsigned short*)alloc((size_t)N * HID * 2);     // 12.8 MB
    // union: h1 (bf16, 12.8 MB, dead after agg1f) under z (f32, 25.6 MB)
    void* uni = alloc((size_t)N * HID * 4);
    unsigned short* h1 = (unsigned short*)uni;
    float* z = (float*)uni;

    k_hist<<<PB, 256, 0, stream>>>(dst, ghist, E, NBUK, EPB);
    k_colscan<<<NBUK, 256, 0, stream>>>(ghist, buktot, NBUK);
    k_bukscan<<<1, 256, 0, stream>>>(buktot, bukstart, NBUK);
    k_bucketize<<<PB, 256, 0, stream>>>(src, dst, ew, ghist, bukstart, sedge, E, NBUK, EPB);
    k_deg<<<NBUK, 256, 0, stream>>>(sedge, bukstart, dinv, N);
    k_gemm1<<<(N + 63) / 64, 256, 0, stream>>>(x, W1, h1, N);
    k_agg1f<<<NBUK, 512, 0, stream>>>(h1, sedge, bukstart, dinv, b1, ybuf, N);
    k_aggzf<<<NBUK, 512, 0, stream>>>(ybuf, sedge, bukstart, dinv, z, N);
    k_gemm2s<<<(N + 63) / 64, 256, 0, stream>>>(z, W2, b2, out, N);
}